// Round 8
// baseline (66.468 us; speedup 1.0000x reference)
//
#include <hip/hip_runtime.h>
#include <cmath>

#define D_ 128
#define B_ 256
#define P_ 64
#define R_ 32
#define NROW (B_*P_*3)   /* 49152 */
#define NBP  (B_*P_)     /* 16384 */
#define EPS_ 1e-8f

typedef unsigned short u16;
typedef unsigned int   u32;
using bf16x8 = __attribute__((ext_vector_type(8))) __bf16;
using f32x4  = __attribute__((ext_vector_type(4))) float;

__device__ __forceinline__ float sigm_f(float x){ return 1.0f/(1.0f + __expf(-x)); }
__device__ __forceinline__ float tanh_f(float x){
    float e = __expf(2.0f*x);
    return 1.0f - 2.0f/(e + 1.0f);
}

__device__ __forceinline__ u16 f2b(float f){         // fp32 -> bf16 RNE
    u32 u = __builtin_bit_cast(u32, f);
    u += 0x7fffu + ((u >> 16) & 1u);
    return (u16)(u >> 16);
}
__device__ __forceinline__ float b2f(u16 s){
    return __builtin_bit_cast(float, ((u32)s) << 16);
}
__device__ __forceinline__ bf16x8 pack8(float a0,float a1,float a2,float a3,
                                        float a4,float a5,float a6,float a7){
    uint4 r;
    r.x = (u32)f2b(a0) | ((u32)f2b(a1) << 16);
    r.y = (u32)f2b(a2) | ((u32)f2b(a3) << 16);
    r.z = (u32)f2b(a4) | ((u32)f2b(a5) << 16);
    r.w = (u32)f2b(a6) | ((u32)f2b(a7) << 16);
    return __builtin_bit_cast(bf16x8, r);
}
__device__ __forceinline__ bf16x8 ldg8(const u16* p){
    return __builtin_bit_cast(bf16x8, *(const uint4*)p);
}
// swizzled LDS bf16 tile: slot(row, granule g) at row*128 + ((g^(row&7))<<3)
__device__ __forceinline__ bf16x8 ldA(const u16* Xs, int row, int gk){
    return __builtin_bit_cast(bf16x8,
        *(const uint4*)(&Xs[row*128 + ((gk ^ (row & 7)) << 3)]));
}
__device__ __forceinline__ int swz_slot(int row, int col){
    return row*128 + (((col >> 3) ^ (row & 7)) << 3) + (col & 7);
}

// ---------------- K1: fused prep + scal + weight-convert (1024 thr) ----------------
__global__ __launch_bounds__(1024) void k_fuse0(
    const int* __restrict__ pair, const int* __restrict__ relset,
    const int* __restrict__ path,
    const float* __restrict__ emb, const float* __restrict__ eu,
    const float* __restrict__ eub,
    const float* __restrict__ wd, const float* __restrict__ we,
    const float* __restrict__ wp, const float* __restrict__ wih,
    const float* __restrict__ whh,
    u16* __restrict__ wdb, u16* __restrict__ web, u16* __restrict__ wpb,
    u16* __restrict__ wib, u16* __restrict__ whb,
    float* __restrict__ sd, float* __restrict__ se)
{
    const int blk = blockIdx.x;
    const int tid = threadIdx.x;

    if (blk >= B_) {           // ---- weight convert region ----
        int i = (blk - B_)*1024 + tid;    // 0..18431
        int e = i*8;
        const float* src; u16* dst; int off;
        if      (e < 16384) { src = wd;  dst = wdb; off = e; }
        else if (e < 32768) { src = we;  dst = web; off = e - 16384; }
        else if (e < 49152) { src = wp;  dst = wpb; off = e - 32768; }
        else if (e < 98304) { src = wih; dst = wib; off = e - 49152; }
        else                { src = whh; dst = whb; off = e - 98304; }
        float4 a = *(const float4*)(src + off);
        float4 b = *(const float4*)(src + off + 4);
        uint4 r;
        r.x = (u32)f2b(a.x) | ((u32)f2b(a.y) << 16);
        r.y = (u32)f2b(a.z) | ((u32)f2b(a.w) << 16);
        r.z = (u32)f2b(b.x) | ((u32)f2b(b.y) << 16);
        r.w = (u32)f2b(b.z) | ((u32)f2b(b.w) << 16);
        *(uint4*)(dst + off) = r;
        return;
    }

    // ---- prep + scal for batch b (16 waves) ----
    const int b    = blk;
    const int wave = tid >> 6, lane = tid & 63;
    __shared__ float s_hts, s_hi, s_ti, s_is;
    __shared__ float s_part[16];

    const float* hp = emb + (size_t)pair[2*b+0]*D_;
    const float* tp = emb + (size_t)pair[2*b+1]*D_;
    float2 hv = *(const float2*)(hp + 2*lane);
    float2 tv = *(const float2*)(tp + 2*lane);
    float2 uv = *(const float2*)(eu + 2*lane);

    if (wave == 0) {
        float dht = hv.x*tv.x + hv.y*tv.y;
        float dhh = hv.x*hv.x + hv.y*hv.y;
        float dtt = tv.x*tv.x + tv.y*tv.y;
        #pragma unroll
        for (int o = 32; o > 0; o >>= 1) {
            dht += __shfl_xor(dht, o);
            dhh += __shfl_xor(dhh, o);
            dtt += __shfl_xor(dtt, o);
        }
        if (lane == 0) {
            float hn = 1.f / fmaxf(sqrtf(dhh), EPS_);
            float tn = 1.f / fmaxf(sqrtf(dtt), EPS_);
            s_hts = dht*hn*tn;
            s_hi  = hn;
            s_ti  = tn;
        }
    }
    // softmax denominator: 2 relset rows per wave
    float accs = 0.f;
    const float eb = eub[0];
    #pragma unroll
    for (int k = 0; k < 2; ++k) {
        const int r = wave*2 + k;
        const float* ep = emb + (size_t)relset[b*R_+r]*D_;
        float2 ev = *(const float2*)(ep + 2*lane);
        float du = ev.x*uv.x + ev.y*uv.y;
        #pragma unroll
        for (int o = 32; o > 0; o >>= 1) du += __shfl_xor(du, o);
        accs += __expf(du + eb);
    }
    if (lane == 0) s_part[wave] = accs;
    __syncthreads();
    if (tid == 0) {
        float s = 0.f;
        #pragma unroll
        for (int w = 0; w < 16; ++w) s += s_part[w];
        s_is = 1.f/s;
    }
    __syncthreads();

    const float hi = s_hi, ti = s_ti, ht = s_hts, is = s_is;

    for (int pp = wave; pp < P_; pp += 16) {
        const int bp = b*P_ + pp;
        const float* e1 = emb + (size_t)path[3*bp+0]*D_;
        const float* e2 = emb + (size_t)path[3*bp+1]*D_;
        const float* e3 = emb + (size_t)path[3*bp+2]*D_;
        float2 v1 = *(const float2*)(e1 + 2*lane);
        float2 v2 = *(const float2*)(e2 + 2*lane);
        float2 v3 = *(const float2*)(e3 + 2*lane);
        float d1h = v1.x*hv.x + v1.y*hv.y;
        float d1t = v1.x*tv.x + v1.y*tv.y;
        float n1  = v1.x*v1.x + v1.y*v1.y;
        float d2h = v2.x*hv.x + v2.y*hv.y;
        float d2t = v2.x*tv.x + v2.y*tv.y;
        float n2  = v2.x*v2.x + v2.y*v2.y;
        float u1 = v1.x*uv.x + v1.y*uv.y;
        float u2 = v2.x*uv.x + v2.y*uv.y;
        float u3 = v3.x*uv.x + v3.y*uv.y;
        #pragma unroll
        for (int o = 32; o > 0; o >>= 1) {
            d1h += __shfl_xor(d1h,o); d1t += __shfl_xor(d1t,o); n1 += __shfl_xor(n1,o);
            d2h += __shfl_xor(d2h,o); d2t += __shfl_xor(d2t,o); n2 += __shfl_xor(n2,o);
            u1  += __shfl_xor(u1,o);  u2  += __shfl_xor(u2,o);  u3 += __shfl_xor(u3,o);
        }
        if (lane == 0) {
            float n1i = 1.f / fmaxf(sqrtf(n1), EPS_);
            float n2i = 1.f / fmaxf(sqrtf(n2), EPS_);
            float se1 = 0.5f*(d1h*hi + d1t*ti)*n1i;
            float se2 = 0.5f*(d2h*hi + d2t*ti)*n2i;
            float sr0 = 0.5f*(ht  + se1);
            float sr1 = 0.5f*(se1 + se2);
            float sr2 = 0.5f*(ht  + se2);
            sd[3*bp+0] = (1.f - sr0)*0.5f;
            sd[3*bp+1] = (1.f - sr1)*0.5f;
            sd[3*bp+2] = (1.f - sr2)*0.5f;
            se[3*bp+0] = expf(u1 + eb)*is;
            se[3*bp+1] = expf(u2 + eb)*is;
            se[3*bp+2] = expf(u3 + eb)*is;
        }
    }
}

// ---------------- K2: fused cost pipeline, MFMA bf16 ----------------
__global__ __launch_bounds__(256,2) void k_cost(
    const int* __restrict__ path, const float* __restrict__ emb,
    const u16* __restrict__ wdb, const float* __restrict__ bd,
    const u16* __restrict__ web, const float* __restrict__ be,
    const u16* __restrict__ wpb, const float* __restrict__ bp,
    const float* __restrict__ sdg, const float* __restrict__ seg,
    u16* __restrict__ relb)
{
    __shared__ u16   Xs[64*128];
    __shared__ float sdS[64], seS[64];
    __shared__ int   pS[64];
    const int tid  = threadIdx.x;
    const int base = blockIdx.x * 64;

    if (tid < 64) {
        pS[tid]  = path[base + tid];
        sdS[tid] = sdg[base + tid];
        seS[tid] = seg[base + tid];
    }
    __syncthreads();

    #pragma unroll
    for (int i = 0; i < 4; ++i) {
        int gid = i*256 + tid;
        int r = gid >> 4, g = gid & 15;
        const float* sp = emb + (size_t)pS[r]*128 + g*8;
        float4 f0 = *(const float4*)sp;
        float4 f1 = *(const float4*)(sp + 4);
        bf16x8 v = pack8(f0.x,f0.y,f0.z,f0.w, f1.x,f1.y,f1.z,f1.w);
        *(uint4*)(&Xs[r*128 + ((g ^ (r & 7)) << 3)]) = __builtin_bit_cast(uint4, v);
    }
    __syncthreads();

    const int wave = tid >> 6, lane = tid & 63;
    const int lrow = lane & 15, lk8 = lane >> 4;
    const int wn = wave;

    f32x4 accD[4][2], accE[4][2];
    #pragma unroll
    for (int m = 0; m < 4; ++m)
        #pragma unroll
        for (int n = 0; n < 2; ++n) { accD[m][n] = (f32x4){0,0,0,0}; accE[m][n] = (f32x4){0,0,0,0}; }

    #pragma unroll
    for (int ks = 0; ks < 4; ++ks) {
        const int gk = ks*4 + lk8;
        bf16x8 a[4];
        #pragma unroll
        for (int mt = 0; mt < 4; ++mt) a[mt] = ldA(Xs, mt*16 + lrow, gk);
        #pragma unroll
        for (int nt = 0; nt < 2; ++nt) {
            const int n = wn*32 + nt*16 + lrow;
            bf16x8 bD = ldg8(wdb + n*128 + gk*8);
            bf16x8 bE = ldg8(web + n*128 + gk*8);
            #pragma unroll
            for (int mt = 0; mt < 4; ++mt) {
                accD[mt][nt] = __builtin_amdgcn_mfma_f32_16x16x32_bf16(a[mt], bD, accD[mt][nt], 0,0,0);
                accE[mt][nt] = __builtin_amdgcn_mfma_f32_16x16x32_bf16(a[mt], bE, accE[mt][nt], 0,0,0);
            }
        }
    }
    __syncthreads();

    #pragma unroll
    for (int nt = 0; nt < 2; ++nt) {
        const int col = wn*32 + nt*16 + lrow;
        const float bde = bd[col] + be[col];
        #pragma unroll
        for (int mt = 0; mt < 4; ++mt) {
            #pragma unroll
            for (int rr = 0; rr < 4; ++rr) {
                const int row = mt*16 + lk8*4 + rr;
                const int sl  = swz_slot(row, col);
                float relv = b2f(Xs[sl]);
                float c = sdS[row]*accD[mt][nt][rr] + seS[row]*accE[mt][nt][rr] + bde;
                Xs[sl] = f2b(relv - 1e-3f*fmaxf(c, 0.f));
            }
        }
    }
    __syncthreads();

    f32x4 accP[4][2];
    #pragma unroll
    for (int m = 0; m < 4; ++m)
        #pragma unroll
        for (int n = 0; n < 2; ++n) accP[m][n] = (f32x4){0,0,0,0};
    #pragma unroll
    for (int ks = 0; ks < 4; ++ks) {
        const int gk = ks*4 + lk8;
        bf16x8 a[4];
        #pragma unroll
        for (int mt = 0; mt < 4; ++mt) a[mt] = ldA(Xs, mt*16 + lrow, gk);
        #pragma unroll
        for (int nt = 0; nt < 2; ++nt) {
            const int n = wn*32 + nt*16 + lrow;
            bf16x8 bP = ldg8(wpb + n*128 + gk*8);
            #pragma unroll
            for (int mt = 0; mt < 4; ++mt)
                accP[mt][nt] = __builtin_amdgcn_mfma_f32_16x16x32_bf16(a[mt], bP, accP[mt][nt], 0,0,0);
        }
    }

    #pragma unroll
    for (int nt = 0; nt < 2; ++nt) {
        const int col = wn*32 + nt*16 + lrow;
        const float bpv = bp[col];
        #pragma unroll
        for (int mt = 0; mt < 4; ++mt) {
            #pragma unroll
            for (int rr = 0; rr < 4; ++rr) {
                const int row  = mt*16 + lk8*4 + rr;
                const int grow = base + row;
                const int tt   = grow - (grow/3)*3;
                const int bprow= grow/3;
                relb[((size_t)tt*NBP + bprow)*128 + col] = f2b(accP[mt][nt][rr] + bpv);
            }
        }
    }
}

// ---- async DMA stage of one 32x128 bf16 x-tile into swizzled LDS ----
// linear LDS dest (lane-ordered), inverse-swizzled global source (rule #21)
__device__ __forceinline__ void stage_x32(const u16* __restrict__ xsl, int bp0,
                                          u16* __restrict__ Xbuf, int tid)
{
    const int G  = tid;                   // granule 0..511 (16B each)
    const int r  = G >> 4, gs = G & 15;
    const u16* src = xsl + (size_t)(bp0 + r)*128 + ((gs ^ (r & 7)) << 3);
    __builtin_amdgcn_global_load_lds(
        (const __attribute__((address_space(1))) void*)src,
        (__attribute__((address_space(3))) void*)(Xbuf + (size_t)G*8),
        16, 0, 0);
}

// ---- GRU gate GEMMs for one step (reads LDS only; weights in regs) ----
template<bool HAS_H>
__device__ __forceinline__ void gru_gates(
    const u16* __restrict__ Xbuf, const u16* __restrict__ Hs,
    int lrow, int lk8,
    const bf16x8* wR, const bf16x8* wZ, const bf16x8* wI,
    const bf16x8* vR, const bf16x8* vZ, const bf16x8* vH,
    f32x4* aR, f32x4* aZ, f32x4* aI, f32x4* aH)
{
    #pragma unroll
    for (int m = 0; m < 2; ++m) {
        aR[m] = (f32x4){0,0,0,0}; aZ[m] = (f32x4){0,0,0,0};
        aI[m] = (f32x4){0,0,0,0}; aH[m] = (f32x4){0,0,0,0};
    }
    #pragma unroll
    for (int ks = 0; ks < 4; ++ks) {
        const int gk = ks*4 + lk8;
        bf16x8 ax[2];
        #pragma unroll
        for (int mt = 0; mt < 2; ++mt) ax[mt] = ldA(Xbuf, mt*16 + lrow, gk);
        #pragma unroll
        for (int mt = 0; mt < 2; ++mt) {
            aR[mt] = __builtin_amdgcn_mfma_f32_16x16x32_bf16(ax[mt], wR[ks], aR[mt], 0,0,0);
            aZ[mt] = __builtin_amdgcn_mfma_f32_16x16x32_bf16(ax[mt], wZ[ks], aZ[mt], 0,0,0);
            aI[mt] = __builtin_amdgcn_mfma_f32_16x16x32_bf16(ax[mt], wI[ks], aI[mt], 0,0,0);
        }
        if (HAS_H) {
            bf16x8 ah[2];
            #pragma unroll
            for (int mt = 0; mt < 2; ++mt) ah[mt] = ldA(Hs, mt*16 + lrow, gk);
            #pragma unroll
            for (int mt = 0; mt < 2; ++mt) {
                aR[mt] = __builtin_amdgcn_mfma_f32_16x16x32_bf16(ah[mt], vR[ks], aR[mt], 0,0,0);
                aZ[mt] = __builtin_amdgcn_mfma_f32_16x16x32_bf16(ah[mt], vZ[ks], aZ[mt], 0,0,0);
                aH[mt] = __builtin_amdgcn_mfma_f32_16x16x32_bf16(ah[mt], vH[ks], aH[mt], 0,0,0);
            }
        }
    }
}

// ---------------- K3: full GRU, 32 rows/block (VGPR-safe), LDS x, reg weights ----------------
// 512 thr (8 waves x 16 cols = 128 cols), 32 rows/block, grid 512.
// Per-lane live set: weights 96 + acc 32 + hreg 8 + transients ~40 => ~180 VGPR (< 256 cap).
__global__ __launch_bounds__(512,2) void k_gru3(
    const u16* __restrict__ relb,    // [3][16384][128] bf16, t-major
    const u16* __restrict__ wib, const u16* __restrict__ whb,
    const float* __restrict__ bih, const float* __restrict__ bhh,
    float* __restrict__ out)
{
    __shared__ u16 X0[32*128];        // 8 KB
    __shared__ u16 X1[32*128];        // 8 KB
    __shared__ u16 X2[32*128];        // 8 KB
    __shared__ u16 Hs[32*128];        // 8 KB
    const int tid  = threadIdx.x;
    const int bp0  = blockIdx.x * 32;
    const int wave = tid >> 6, lane = tid & 63;
    const int lrow = lane & 15, lk8 = lane >> 4;
    const int col  = wave*16 + lrow;

    // issue all three x-tile DMAs first (latency overlapped with weight loads)
    stage_x32(relb,                     bp0, X0, tid);
    stage_x32(relb + (size_t)NBP*128,   bp0, X1, tid);
    stage_x32(relb + (size_t)2*NBP*128, bp0, X2, tid);

    // ---- weight fragments in registers (loaded once) ----
    bf16x8 wR[4], wZ[4], wI[4], vR[4], vZ[4], vH[4];
    #pragma unroll
    for (int ks = 0; ks < 4; ++ks) {
        const int gk = ks*4 + lk8;
        wR[ks] = ldg8(wib +             col*128 + gk*8);
        wZ[ks] = ldg8(wib + 16384     + col*128 + gk*8);
        wI[ks] = ldg8(wib + 2*16384   + col*128 + gk*8);
        vR[ks] = ldg8(whb +             col*128 + gk*8);
        vZ[ks] = ldg8(whb + 16384     + col*128 + gk*8);
        vH[ks] = ldg8(whb + 2*16384   + col*128 + gk*8);
    }
    const float brv = bih[col]       + bhh[col];
    const float bzv = bih[128 + col] + bhh[128 + col];
    const float biN = bih[256 + col];
    const float bhN = bhh[256 + col];

    float hreg[2][4];
    #pragma unroll
    for (int m = 0; m < 2; ++m)
        #pragma unroll
        for (int r = 0; r < 4; ++r) hreg[m][r] = 0.f;

    f32x4 aR[2], aZ[2], aI[2], aH[2];

    __syncthreads();                  // B1: X0..X2 + weights ready

    // ---- t = 0 (h = 0: x-side only) ----
    gru_gates<false>(X0, Hs, lrow, lk8, wR, wZ, wI, vR, vZ, vH, aR, aZ, aI, aH);
    #pragma unroll
    for (int mt = 0; mt < 2; ++mt)
        #pragma unroll
        for (int rr = 0; rr < 4; ++rr) {
            const int row = mt*16 + lk8*4 + rr;
            float rv = sigm_f(aR[mt][rr] + brv);
            float zv = sigm_f(aZ[mt][rr] + bzv);
            float nn = tanh_f(aI[mt][rr] + biN + rv*bhN);
            float h2 = (1.f - zv)*nn;
            hreg[mt][rr] = h2;
            Hs[swz_slot(row, col)] = f2b(h2);
        }
    __syncthreads();                  // B2: Hs(t0) visible

    // ---- t = 1 ----
    gru_gates<true>(X1, Hs, lrow, lk8, wR, wZ, wI, vR, vZ, vH, aR, aZ, aI, aH);
    __syncthreads();                  // B3: all Hs(t0) reads done
    #pragma unroll
    for (int mt = 0; mt < 2; ++mt)
        #pragma unroll
        for (int rr = 0; rr < 4; ++rr) {
            const int row = mt*16 + lk8*4 + rr;
            float rv = sigm_f(aR[mt][rr] + brv);
            float zv = sigm_f(aZ[mt][rr] + bzv);
            float hn = aH[mt][rr] + bhN;
            float nn = tanh_f(aI[mt][rr] + biN + rv*hn);
            float h2 = (1.f - zv)*nn + zv*hreg[mt][rr];
            hreg[mt][rr] = h2;
            Hs[swz_slot(row, col)] = f2b(h2);
        }
    __syncthreads();                  // B4: Hs(t1) visible

    // ---- t = 2 ----
    gru_gates<true>(X2, Hs, lrow, lk8, wR, wZ, wI, vR, vZ, vH, aR, aZ, aI, aH);
    #pragma unroll
    for (int mt = 0; mt < 2; ++mt)
        #pragma unroll
        for (int rr = 0; rr < 4; ++rr) {
            const int row = mt*16 + lk8*4 + rr;
            float rv = sigm_f(aR[mt][rr] + brv);
            float zv = sigm_f(aZ[mt][rr] + bzv);
            float hn = aH[mt][rr] + bhN;
            float nn = tanh_f(aI[mt][rr] + biN + rv*hn);
            float h2 = (1.f - zv)*nn + zv*hreg[mt][rr];
            out[(size_t)(bp0 + row)*128 + col] = h2;
        }
}

extern "C" void kernel_launch(void* const* d_in, const int* in_sizes, int n_in,
                              void* d_out, int out_size, void* d_ws, size_t ws_size,
                              hipStream_t stream)
{
    const int*   path   = (const int*)d_in[0];
    const int*   pair   = (const int*)d_in[1];
    const int*   relset = (const int*)d_in[2];
    const float* emb    = (const float*)d_in[3];
    const float* wd     = (const float*)d_in[4];
    const float* bd     = (const float*)d_in[5];
    const float* we     = (const float*)d_in[6];
    const float* be     = (const float*)d_in[7];
    const float* wp     = (const float*)d_in[8];
    const float* bp     = (const float*)d_in[9];
    const float* eu     = (const float*)d_in[10];
    const float* eub    = (const float*)d_in[11];
    const float* wih    = (const float*)d_in[12];
    const float* whh    = (const float*)d_in[13];
    const float* bih    = (const float*)d_in[14];
    const float* bhh    = (const float*)d_in[15];
    float* out = (float*)d_out;
    float* ws  = (float*)d_ws;

    // workspace (float offsets), total ~12.7 MB
    float* sdg  = ws;                      // 49152
    float* seg  = ws + NROW;               // 49152 -> ends 98304
    u16*   relb = (u16*)(ws + 98304);      // 3*16384*128 bf16 -> ends 3244032
    u16*   wdb  = (u16*)(ws + 3244032);    // -> 3252224
    u16*   web  = (u16*)(ws + 3252224);    // -> 3260416
    u16*   wpb  = (u16*)(ws + 3260416);    // -> 3268608
    u16*   wib  = (u16*)(ws + 3268608);    // -> 3293184
    u16*   whb  = (u16*)(ws + 3293184);    // -> 3317760 (12.7 MB)

    k_fuse0<<<B_ + 18, 1024, 0, stream>>>(pair, relset, path, emb, eu, eub,
                                          wd, we, wp, wih, whh,
                                          wdb, web, wpb, wib, whb, sdg, seg);
    k_cost <<<NROW/64,  256, 0, stream>>>(path, emb, wdb, bd, web, be, wpb, bp,
                                          sdg, seg, relb);
    k_gru3 <<<NBP/32,   512, 0, stream>>>(relb, wib, whb, bih, bhh, out);
}

// Round 9
// 48.123 us; speedup vs baseline: 1.3812x; 1.3812x over previous
//
#include <hip/hip_runtime.h>
#include <cmath>

#define D_ 128
#define B_ 256
#define P_ 64
#define R_ 32
#define NROW (B_*P_*3)   /* 49152 */
#define NBP  (B_*P_)     /* 16384 */
#define GROWS 192        /* rel rows per batch */
#define EPS_ 1e-8f

typedef unsigned short u16;
typedef unsigned int   u32;
using bf16x8 = __attribute__((ext_vector_type(8))) __bf16;
using f32x4  = __attribute__((ext_vector_type(4))) float;

__device__ __forceinline__ float sigm_f(float x){ return 1.0f/(1.0f + __expf(-x)); }
__device__ __forceinline__ float tanh_f(float x){
    float e = __expf(2.0f*x);
    return 1.0f - 2.0f/(e + 1.0f);
}

__device__ __forceinline__ u16 f2b(float f){         // fp32 -> bf16 RNE
    u32 u = __builtin_bit_cast(u32, f);
    u += 0x7fffu + ((u >> 16) & 1u);
    return (u16)(u >> 16);
}
__device__ __forceinline__ float b2f(u16 s){
    return __builtin_bit_cast(float, ((u32)s) << 16);
}
__device__ __forceinline__ bf16x8 pack8(float a0,float a1,float a2,float a3,
                                        float a4,float a5,float a6,float a7){
    uint4 r;
    r.x = (u32)f2b(a0) | ((u32)f2b(a1) << 16);
    r.y = (u32)f2b(a2) | ((u32)f2b(a3) << 16);
    r.z = (u32)f2b(a4) | ((u32)f2b(a5) << 16);
    r.w = (u32)f2b(a6) | ((u32)f2b(a7) << 16);
    return __builtin_bit_cast(bf16x8, r);
}
__device__ __forceinline__ bf16x8 ldg8(const u16* p){
    return __builtin_bit_cast(bf16x8, *(const uint4*)p);
}
// swizzled LDS bf16 tile: slot(row, granule g) at row*128 + ((g^(row&7))<<3)
__device__ __forceinline__ bf16x8 ldA(const u16* Xs, int row, int gk){
    return __builtin_bit_cast(bf16x8,
        *(const uint4*)(&Xs[row*128 + ((gk ^ (row & 7)) << 3)]));
}
__device__ __forceinline__ int swz_slot(int row, int col){
    return row*128 + (((col >> 3) ^ (row & 7)) << 3) + (col & 7);
}

// ---------------- K1: weight convert fp32 -> bf16 ----------------
__global__ __launch_bounds__(1024) void k_wcvt(
    const float* __restrict__ wd, const float* __restrict__ we,
    const float* __restrict__ wp, const float* __restrict__ wih,
    const float* __restrict__ whh,
    u16* __restrict__ wdb, u16* __restrict__ web, u16* __restrict__ wpb,
    u16* __restrict__ wib, u16* __restrict__ whb)
{
    int i = blockIdx.x*1024 + threadIdx.x;    // 0..18431
    int e = i*8;
    const float* src; u16* dst; int off;
    if      (e < 16384) { src = wd;  dst = wdb; off = e; }
    else if (e < 32768) { src = we;  dst = web; off = e - 16384; }
    else if (e < 49152) { src = wp;  dst = wpb; off = e - 32768; }
    else if (e < 98304) { src = wih; dst = wib; off = e - 49152; }
    else                { src = whh; dst = whb; off = e - 98304; }
    float4 a = *(const float4*)(src + off);
    float4 b = *(const float4*)(src + off + 4);
    uint4 r;
    r.x = (u32)f2b(a.x) | ((u32)f2b(a.y) << 16);
    r.y = (u32)f2b(a.z) | ((u32)f2b(a.w) << 16);
    r.z = (u32)f2b(b.x) | ((u32)f2b(b.y) << 16);
    r.w = (u32)f2b(b.z) | ((u32)f2b(b.w) << 16);
    *(uint4*)(dst + off) = r;
}

// ---------------- K2: per-batch mega kernel ----------------
// grid 256 (1 block/CU), 512 thr (8 waves). Each wave owns a 16-col strip.
__global__ __launch_bounds__(512,2) void k_mega(
    const int* __restrict__ pair, const int* __restrict__ relset,
    const int* __restrict__ path,
    const float* __restrict__ emb, const float* __restrict__ eu,
    const float* __restrict__ eub,
    const u16* __restrict__ wdb, const float* __restrict__ bd,
    const u16* __restrict__ web, const float* __restrict__ be,
    const u16* __restrict__ wpb, const float* __restrict__ bpv_,
    const u16* __restrict__ wib, const u16* __restrict__ whb,
    const float* __restrict__ bih, const float* __restrict__ bhh,
    float* __restrict__ out)
{
    __shared__ u16   Xs[GROWS*128];          // 48 KB rel tile (swizzled bf16)
    __shared__ u16   Hs[64*128];             // 16 KB GRU state
    __shared__ int   pS[GROWS];
    __shared__ float pdh[GROWS], pdt[GROWS], pdu[GROWS], pnn[GROWS];
    __shared__ float sdS[GROWS], seS[GROWS];
    __shared__ float s_hts, s_hi, s_ti;
    __shared__ float s_part[8];

    const int b    = blockIdx.x;
    const int tid  = threadIdx.x;
    const int wave = tid >> 6, lane = tid & 63;
    const int lrow = lane & 15, lk8 = lane >> 4;
    const int col  = wave*16 + lrow;
    const float eb = eub[0];

    // ---- P0: path indices + early cost-weight fragment loads ----
    if (tid < GROWS) pS[tid] = path[b*GROWS + tid];
    bf16x8 fD[4], fE[4], fP[4];
    #pragma unroll
    for (int ks = 0; ks < 4; ++ks) {
        const int gk = ks*4 + lk8;
        fD[ks] = ldg8(wdb + col*128 + gk*8);
        fE[ks] = ldg8(web + col*128 + gk*8);
        fP[ks] = ldg8(wpb + col*128 + gk*8);
    }
    const int ph = pair[2*b], ptl = pair[2*b+1];
    __syncthreads();

    // ---- P1: gather 192 rel rows -> Xs; pair stats; relset denom ----
    {
        #pragma unroll
        for (int i = 0; i < 6; ++i) {
            int gid = i*512 + tid;              // 3072 granules
            int r = gid >> 4, g = gid & 15;
            const float* sp = emb + (size_t)pS[r]*128 + g*8;
            float4 f0 = *(const float4*)sp;
            float4 f1 = *(const float4*)(sp + 4);
            bf16x8 v = pack8(f0.x,f0.y,f0.z,f0.w, f1.x,f1.y,f1.z,f1.w);
            *(uint4*)(&Xs[r*128 + ((g ^ (r & 7)) << 3)]) = __builtin_bit_cast(uint4, v);
        }
        if (wave == 0) {
            float2 hv2 = *(const float2*)(emb + (size_t)ph*128 + 2*lane);
            float2 tv2 = *(const float2*)(emb + (size_t)ptl*128 + 2*lane);
            float dht = hv2.x*tv2.x + hv2.y*tv2.y;
            float dhh = hv2.x*hv2.x + hv2.y*hv2.y;
            float dtt = tv2.x*tv2.x + tv2.y*tv2.y;
            #pragma unroll
            for (int o = 32; o > 0; o >>= 1) {
                dht += __shfl_xor(dht, o);
                dhh += __shfl_xor(dhh, o);
                dtt += __shfl_xor(dtt, o);
            }
            if (lane == 0) {
                float hn = 1.f / fmaxf(sqrtf(dhh), EPS_);
                float tn = 1.f / fmaxf(sqrtf(dtt), EPS_);
                s_hts = dht*hn*tn;
                s_hi  = hn;
                s_ti  = tn;
            }
        }
        // softmax denominator: 4 relset rows per wave
        float2 uv2 = *(const float2*)(eu + 2*lane);
        float accs = 0.f;
        #pragma unroll
        for (int k = 0; k < 4; ++k) {
            const int ri = relset[b*R_ + wave*4 + k];
            float2 ev = *(const float2*)(emb + (size_t)ri*128 + 2*lane);
            float du = ev.x*uv2.x + ev.y*uv2.y;
            #pragma unroll
            for (int o = 32; o > 0; o >>= 1) du += __shfl_xor(du, o);
            accs += __expf(du + eb);
        }
        if (lane == 0) s_part[wave] = accs;
    }
    __syncthreads();

    // ---- P2: per-row partials from staged tile (16 lanes per row) ----
    {
        const int sub = lane >> 4, l16 = lane & 15;
        const float* hpq = emb + (size_t)ph*128  + l16*8;
        const float* tpq = emb + (size_t)ptl*128 + l16*8;
        const float* upq = eu + l16*8;
        float hq[8], tq[8], uq[8];
        {
            float4 a0 = *(const float4*)hpq, a1 = *(const float4*)(hpq+4);
            float4 b0 = *(const float4*)tpq, b1 = *(const float4*)(tpq+4);
            float4 c0 = *(const float4*)upq, c1 = *(const float4*)(upq+4);
            hq[0]=a0.x;hq[1]=a0.y;hq[2]=a0.z;hq[3]=a0.w;hq[4]=a1.x;hq[5]=a1.y;hq[6]=a1.z;hq[7]=a1.w;
            tq[0]=b0.x;tq[1]=b0.y;tq[2]=b0.z;tq[3]=b0.w;tq[4]=b1.x;tq[5]=b1.y;tq[6]=b1.z;tq[7]=b1.w;
            uq[0]=c0.x;uq[1]=c0.y;uq[2]=c0.z;uq[3]=c0.w;uq[4]=c1.x;uq[5]=c1.y;uq[6]=c1.z;uq[7]=c1.w;
        }
        #pragma unroll
        for (int i = 0; i < 6; ++i) {
            const int r = wave*24 + i*4 + sub;
            uint4 gv = *(const uint4*)(&Xs[r*128 + ((l16 ^ (r & 7)) << 3)]);
            float v[8];
            v[0]=b2f((u16)(gv.x&0xffff)); v[1]=b2f((u16)(gv.x>>16));
            v[2]=b2f((u16)(gv.y&0xffff)); v[3]=b2f((u16)(gv.y>>16));
            v[4]=b2f((u16)(gv.z&0xffff)); v[5]=b2f((u16)(gv.z>>16));
            v[6]=b2f((u16)(gv.w&0xffff)); v[7]=b2f((u16)(gv.w>>16));
            float dh=0.f, dt=0.f, du=0.f, nn=0.f;
            #pragma unroll
            for (int j = 0; j < 8; ++j) {
                dh = fmaf(v[j], hq[j], dh);
                dt = fmaf(v[j], tq[j], dt);
                du = fmaf(v[j], uq[j], du);
                nn = fmaf(v[j], v[j], nn);
            }
            #pragma unroll
            for (int o = 8; o > 0; o >>= 1) {
                dh += __shfl_xor(dh, o);
                dt += __shfl_xor(dt, o);
                du += __shfl_xor(du, o);
                nn += __shfl_xor(nn, o);
            }
            if (l16 == 0) { pdh[r]=dh; pdt[r]=dt; pdu[r]=du; pnn[r]=nn; }
        }
    }
    __syncthreads();

    // ---- P3: sd/se scalars (thread p = tid < 64) ----
    if (tid < 64) {
        float is = 0.f;
        #pragma unroll
        for (int w = 0; w < 8; ++w) is += s_part[w];
        is = 1.f/is;
        const float hi = s_hi, ti = s_ti, ht = s_hts;
        const int r1 = 3*tid, r2 = r1+1, r3 = r1+2;
        float n1i = 1.f / fmaxf(sqrtf(pnn[r1]), EPS_);
        float n2i = 1.f / fmaxf(sqrtf(pnn[r2]), EPS_);
        float se1 = 0.5f*(pdh[r1]*hi + pdt[r1]*ti)*n1i;
        float se2 = 0.5f*(pdh[r2]*hi + pdt[r2]*ti)*n2i;
        sdS[r1] = (1.f - 0.5f*(ht  + se1))*0.5f;
        sdS[r2] = (1.f - 0.5f*(se1 + se2))*0.5f;
        sdS[r3] = (1.f - 0.5f*(ht  + se2))*0.5f;
        seS[r1] = expf(pdu[r1] + eb)*is;
        seS[r2] = expf(pdu[r2] + eb)*is;
        seS[r3] = expf(pdu[r3] + eb)*is;
    }
    __syncthreads();

    // ---- P4a: D/E GEMMs + cost epilogue (in-place on Xs) ----
    {
        f32x4 aD[12], aE[12];
        #pragma unroll
        for (int m = 0; m < 12; ++m) { aD[m] = (f32x4){0,0,0,0}; aE[m] = (f32x4){0,0,0,0}; }
        #pragma unroll
        for (int ks = 0; ks < 4; ++ks) {
            const int gk = ks*4 + lk8;
            #pragma unroll
            for (int mt = 0; mt < 12; ++mt) {
                bf16x8 a = ldA(Xs, mt*16 + lrow, gk);
                aD[mt] = __builtin_amdgcn_mfma_f32_16x16x32_bf16(a, fD[ks], aD[mt], 0,0,0);
                aE[mt] = __builtin_amdgcn_mfma_f32_16x16x32_bf16(a, fE[ks], aE[mt], 0,0,0);
            }
        }
        __syncthreads();              // all D/E reads of Xs done
        const float bde = bd[col] + be[col];
        #pragma unroll
        for (int mt = 0; mt < 12; ++mt) {
            #pragma unroll
            for (int rr = 0; rr < 4; ++rr) {
                const int row = mt*16 + lk8*4 + rr;
                const int sl  = swz_slot(row, col);
                float relv = b2f(Xs[sl]);
                float c = sdS[row]*aD[mt][rr] + seS[row]*aE[mt][rr] + bde;
                Xs[sl] = f2b(relv - 1e-3f*fmaxf(c, 0.f));
            }
        }
    }
    __syncthreads();

    // ---- P4b: P GEMM -> rel_in (in-place on Xs) ----
    {
        f32x4 aP[12];
        #pragma unroll
        for (int m = 0; m < 12; ++m) aP[m] = (f32x4){0,0,0,0};
        #pragma unroll
        for (int ks = 0; ks < 4; ++ks) {
            const int gk = ks*4 + lk8;
            #pragma unroll
            for (int mt = 0; mt < 12; ++mt) {
                bf16x8 a = ldA(Xs, mt*16 + lrow, gk);
                aP[mt] = __builtin_amdgcn_mfma_f32_16x16x32_bf16(a, fP[ks], aP[mt], 0,0,0);
            }
        }
        __syncthreads();              // all P reads of Xs done
        const float bpv = bpv_[col];
        #pragma unroll
        for (int mt = 0; mt < 12; ++mt) {
            #pragma unroll
            for (int rr = 0; rr < 4; ++rr) {
                const int row = mt*16 + lk8*4 + rr;
                Xs[swz_slot(row, col)] = f2b(aP[mt][rr] + bpv);
            }
        }
    }
    __syncthreads();

    // ---- P5: GRU over 64 bp rows, x = Xs rows 3m+t, h in Hs ----
    bf16x8 wR[4], wZ[4], wI[4], vR[4], vZ[4], vH[4];
    #pragma unroll
    for (int ks = 0; ks < 4; ++ks) {
        const int gk = ks*4 + lk8;
        wR[ks] = ldg8(wib +           col*128 + gk*8);
        wZ[ks] = ldg8(wib + 16384   + col*128 + gk*8);
        wI[ks] = ldg8(wib + 2*16384 + col*128 + gk*8);
        vR[ks] = ldg8(whb +           col*128 + gk*8);
        vZ[ks] = ldg8(whb + 16384   + col*128 + gk*8);
        vH[ks] = ldg8(whb + 2*16384 + col*128 + gk*8);
    }
    const float brv = bih[col]       + bhh[col];
    const float bzv = bih[128 + col] + bhh[128 + col];
    const float biN = bih[256 + col];
    const float bhN = bhh[256 + col];

    float hreg[4][4];
    f32x4 aR[4], aZ[4], aI[4], aH[4];

    // t = 0 (h = 0)
    #pragma unroll
    for (int m = 0; m < 4; ++m) { aR[m]=(f32x4){0,0,0,0}; aZ[m]=(f32x4){0,0,0,0}; aI[m]=(f32x4){0,0,0,0}; }
    #pragma unroll
    for (int ks = 0; ks < 4; ++ks) {
        const int gk = ks*4 + lk8;
        #pragma unroll
        for (int mt = 0; mt < 4; ++mt) {
            bf16x8 ax = ldA(Xs, 3*(mt*16 + lrow) + 0, gk);
            aR[mt] = __builtin_amdgcn_mfma_f32_16x16x32_bf16(ax, wR[ks], aR[mt], 0,0,0);
            aZ[mt] = __builtin_amdgcn_mfma_f32_16x16x32_bf16(ax, wZ[ks], aZ[mt], 0,0,0);
            aI[mt] = __builtin_amdgcn_mfma_f32_16x16x32_bf16(ax, wI[ks], aI[mt], 0,0,0);
        }
    }
    #pragma unroll
    for (int mt = 0; mt < 4; ++mt)
        #pragma unroll
        for (int rr = 0; rr < 4; ++rr) {
            const int row = mt*16 + lk8*4 + rr;
            float rv = sigm_f(aR[mt][rr] + brv);
            float zv = sigm_f(aZ[mt][rr] + bzv);
            float nn = tanh_f(aI[mt][rr] + biN + rv*bhN);
            float h2 = (1.f - zv)*nn;
            hreg[mt][rr] = h2;
            Hs[swz_slot(row, col)] = f2b(h2);
        }
    __syncthreads();

    // t = 1
    #pragma unroll
    for (int m = 0; m < 4; ++m) { aR[m]=(f32x4){0,0,0,0}; aZ[m]=(f32x4){0,0,0,0}; aI[m]=(f32x4){0,0,0,0}; aH[m]=(f32x4){0,0,0,0}; }
    #pragma unroll
    for (int ks = 0; ks < 4; ++ks) {
        const int gk = ks*4 + lk8;
        #pragma unroll
        for (int mt = 0; mt < 4; ++mt) {
            bf16x8 ax = ldA(Xs, 3*(mt*16 + lrow) + 1, gk);
            bf16x8 ah = ldA(Hs, mt*16 + lrow, gk);
            aR[mt] = __builtin_amdgcn_mfma_f32_16x16x32_bf16(ax, wR[ks], aR[mt], 0,0,0);
            aZ[mt] = __builtin_amdgcn_mfma_f32_16x16x32_bf16(ax, wZ[ks], aZ[mt], 0,0,0);
            aI[mt] = __builtin_amdgcn_mfma_f32_16x16x32_bf16(ax, wI[ks], aI[mt], 0,0,0);
            aR[mt] = __builtin_amdgcn_mfma_f32_16x16x32_bf16(ah, vR[ks], aR[mt], 0,0,0);
            aZ[mt] = __builtin_amdgcn_mfma_f32_16x16x32_bf16(ah, vZ[ks], aZ[mt], 0,0,0);
            aH[mt] = __builtin_amdgcn_mfma_f32_16x16x32_bf16(ah, vH[ks], aH[mt], 0,0,0);
        }
    }
    __syncthreads();                  // all Hs(t0) reads complete
    #pragma unroll
    for (int mt = 0; mt < 4; ++mt)
        #pragma unroll
        for (int rr = 0; rr < 4; ++rr) {
            const int row = mt*16 + lk8*4 + rr;
            float rv = sigm_f(aR[mt][rr] + brv);
            float zv = sigm_f(aZ[mt][rr] + bzv);
            float hn = aH[mt][rr] + bhN;
            float nn = tanh_f(aI[mt][rr] + biN + rv*hn);
            float h2 = (1.f - zv)*nn + zv*hreg[mt][rr];
            hreg[mt][rr] = h2;
            Hs[swz_slot(row, col)] = f2b(h2);
        }
    __syncthreads();

    // t = 2 -> out
    #pragma unroll
    for (int m = 0; m < 4; ++m) { aR[m]=(f32x4){0,0,0,0}; aZ[m]=(f32x4){0,0,0,0}; aI[m]=(f32x4){0,0,0,0}; aH[m]=(f32x4){0,0,0,0}; }
    #pragma unroll
    for (int ks = 0; ks < 4; ++ks) {
        const int gk = ks*4 + lk8;
        #pragma unroll
        for (int mt = 0; mt < 4; ++mt) {
            bf16x8 ax = ldA(Xs, 3*(mt*16 + lrow) + 2, gk);
            bf16x8 ah = ldA(Hs, mt*16 + lrow, gk);
            aR[mt] = __builtin_amdgcn_mfma_f32_16x16x32_bf16(ax, wR[ks], aR[mt], 0,0,0);
            aZ[mt] = __builtin_amdgcn_mfma_f32_16x16x32_bf16(ax, wZ[ks], aZ[mt], 0,0,0);
            aI[mt] = __builtin_amdgcn_mfma_f32_16x16x32_bf16(ax, wI[ks], aI[mt], 0,0,0);
            aR[mt] = __builtin_amdgcn_mfma_f32_16x16x32_bf16(ah, vR[ks], aR[mt], 0,0,0);
            aZ[mt] = __builtin_amdgcn_mfma_f32_16x16x32_bf16(ah, vZ[ks], aZ[mt], 0,0,0);
            aH[mt] = __builtin_amdgcn_mfma_f32_16x16x32_bf16(ah, vH[ks], aH[mt], 0,0,0);
        }
    }
    const int bp0 = b*64;
    #pragma unroll
    for (int mt = 0; mt < 4; ++mt)
        #pragma unroll
        for (int rr = 0; rr < 4; ++rr) {
            const int row = mt*16 + lk8*4 + rr;
            float rv = sigm_f(aR[mt][rr] + brv);
            float zv = sigm_f(aZ[mt][rr] + bzv);
            float hn = aH[mt][rr] + bhN;
            float nn = tanh_f(aI[mt][rr] + biN + rv*hn);
            float h2 = (1.f - zv)*nn + zv*hreg[mt][rr];
            out[(size_t)(bp0 + row)*128 + col] = h2;
        }
}

extern "C" void kernel_launch(void* const* d_in, const int* in_sizes, int n_in,
                              void* d_out, int out_size, void* d_ws, size_t ws_size,
                              hipStream_t stream)
{
    const int*   path   = (const int*)d_in[0];
    const int*   pair   = (const int*)d_in[1];
    const int*   relset = (const int*)d_in[2];
    const float* emb    = (const float*)d_in[3];
    const float* wd     = (const float*)d_in[4];
    const float* bd     = (const float*)d_in[5];
    const float* we     = (const float*)d_in[6];
    const float* be     = (const float*)d_in[7];
    const float* wp     = (const float*)d_in[8];
    const float* bp     = (const float*)d_in[9];
    const float* eu     = (const float*)d_in[10];
    const float* eub    = (const float*)d_in[11];
    const float* wih    = (const float*)d_in[12];
    const float* whh    = (const float*)d_in[13];
    const float* bih    = (const float*)d_in[14];
    const float* bhh    = (const float*)d_in[15];
    float* out = (float*)d_out;
    float* ws  = (float*)d_ws;

    // workspace: only bf16 weights (~288 KB)
    u16* wdb = (u16*)ws;               // 16384 u16
    u16* web = wdb + 16384;
    u16* wpb = web + 16384;
    u16* wib = wpb + 16384;            // 49152 u16
    u16* whb = wib + 49152;            // ends at 147456 u16 = 288 KB

    k_wcvt<<<18, 1024, 0, stream>>>(wd, we, wp, wih, whh, wdb, web, wpb, wib, whb);
    k_mega<<<B_, 512, 0, stream>>>(pair, relset, path, emb, eu, eub,
                                   wdb, bd, web, be, wpb, bp,
                                   wib, whb, bih, bhh, out);
}